// Round 18
// baseline (259.191 us; speedup 1.0000x reference)
//
#include <hip/hip_runtime.h>
#include <hip/hip_bf16.h>

using short8 = __attribute__((ext_vector_type(8))) short;
using f32x4  = __attribute__((ext_vector_type(4))) float;
using f32x2  = __attribute__((ext_vector_type(2))) float;
typedef unsigned int u32;

static constexpr int NN = 65536;   // nodes
static constexpr int F  = 256;     // feat dim
static constexpr int KE = 8;       // experts
static constexpr int KD = KE * F;  // 2048 = GEMM inner dim
static constexpr int NB = 256;     // coarse buckets (row>>8)
static constexpr int EPB = 8192;   // edges per bucket_scatter block
static constexpr int BCAP = 12288; // fixed bucket capacity (mean 8192 + 45 sigma)

__device__ __forceinline__ short f2bf(float f) {
    union { __hip_bfloat16 h; short s; } u;
    u.h = __float2bfloat16(f);
    return u.s;
}

// ---------- x f32 -> xq fp8 e4m3; block 0 also initializes bucket cursors
__global__ __launch_bounds__(256)
void conv_x8(const float* __restrict__ x, u32* __restrict__ xq,
             int* __restrict__ bcursor) {
    if (blockIdx.x == 0 && threadIdx.x < NB)
        bcursor[threadIdx.x] = threadIdx.x * BCAP;
    const size_t i = ((size_t)blockIdx.x * 256 + threadIdx.x) * 8;
    const float4 a = *(const float4*)(x + i);
    const float4 b = *(const float4*)(x + i + 4);
    u32 w0 = __builtin_amdgcn_cvt_pk_fp8_f32(a.x, a.y, 0, false);
    w0     = __builtin_amdgcn_cvt_pk_fp8_f32(a.z, a.w, w0, true);
    u32 w1 = __builtin_amdgcn_cvt_pk_fp8_f32(b.x, b.y, 0, false);
    w1     = __builtin_amdgcn_cvt_pk_fp8_f32(b.z, b.w, w1, true);
    *(uint2*)(xq + i / 4) = make_uint2(w0, w1);
}

// ---------- W [8][256][256] f32 -> WbT fragment-major bf16 (round-12 layout,
// correctness-proven): chunk = ((wc*32 + s)*8 + nk) of 64 lanes x 16B, where
// s = e*4 + i0b, nk = ni*2+ks, lane = hi2*16+lr holds
// W[e][i0b*64 + ks*32 + hi2*8 + j][wc*64 + ni*16 + lr], j=0..7.
__global__ void prep_w(const float* __restrict__ W, short* __restrict__ WbT) {
    __shared__ float tile[64][65];
    const int e   = blockIdx.z;
    const int i0b = blockIdx.x;         // i-tile
    const int wc  = blockIdx.y;         // o-tile
    const int c  = threadIdx.x & 63;
    const int r4 = threadIdx.x >> 6;
    for (int rr = r4; rr < 64; rr += 4)
        tile[rr][c] = W[((size_t)e * F + i0b * 64 + rr) * F + wc * 64 + c];
    __syncthreads();
    const int s = e * 4 + i0b;
    #pragma unroll
    for (int q = 0; q < 2; ++q) {
        const int ci   = threadIdx.x + q * 256;   // 0..511
        const int nk   = ci >> 6;
        const int lane = ci & 63;
        const int ni = nk >> 1, ks = nk & 1;
        const int hi2 = lane >> 4, lr = lane & 15;
        const int o_l = ni * 16 + lr;
        const int i_l = ks * 32 + hi2 * 8;
        short8 pk;
        #pragma unroll
        for (int j = 0; j < 8; ++j) pk[j] = f2bf(tile[i_l + j][o_l]);
        *(short8*)(WbT + ((((size_t)(wc * 32 + s) * 8 + nk) << 6) + lane) * 8) = pk;
    }
}

// ---------- scatter edges into FIXED-CAPACITY coarse buckets
__global__ __launch_bounds__(256)
void bucket_scatter(const int* __restrict__ rows, const int* __restrict__ cols,
                    const float* __restrict__ vals, int* __restrict__ bcursor,
                    int2* __restrict__ tmp, int E) {
    __shared__ int h[NB], wb[NB];
    const int tid = threadIdx.x;
    h[tid] = 0;
    __syncthreads();
    const int base = blockIdx.x * EPB;
    const int lim  = min(EPB, E - base);
    for (int i = tid; i < lim; i += 256)
        atomicAdd(&h[rows[base + i] >> 8], 1);
    __syncthreads();
    const int c = h[tid];
    wb[tid] = c ? atomicAdd(&bcursor[tid], c) : 0;
    h[tid] = 0;
    __syncthreads();
    for (int i = tid; i < lim; i += 256) {
        const int r  = rows[base + i];
        const int bk = r >> 8;
        const int rank = atomicAdd(&h[bk], 1);
        tmp[wb[bk] + rank] = make_int2(((r & 255) << 16) | cols[base + i],
                                       __float_as_int(vals[base + i]));
    }
}

// ---------- one block per bucket: exact-row sort (in place) + row starts/ends
__global__ __launch_bounds__(256)
void bucket_to_csr(const int* __restrict__ bcursor, int2* __restrict__ tmp,
                   int* __restrict__ offsets, int* __restrict__ rend) {
    __shared__ int2 buf[BCAP];          // 96 KB
    __shared__ int h[NB], off[NB];
    const int tid = threadIdx.x;
    const int k   = blockIdx.x;
    const int beg = k * BCAP;
    const int n   = bcursor[k] - beg;
    h[tid] = 0;
    __syncthreads();
    for (int i = tid; i < n; i += 256) {
        const int2 e = tmp[beg + i];
        if (i < BCAP) buf[i] = e;
        atomicAdd(&h[e.x >> 16], 1);
    }
    __syncthreads();
    const int c = h[tid];
    off[tid] = c;
    __syncthreads();
    for (int o = 1; o < NB; o <<= 1) {
        int v = (tid >= o) ? off[tid - o] : 0;
        __syncthreads();
        off[tid] += v;
        __syncthreads();
    }
    const int excl = off[tid] - c;
    offsets[k * NB + tid] = beg + excl;
    rend[k * NB + tid]    = beg + excl + c;
    h[tid] = excl;                      // reuse as within-bucket cursor
    __syncthreads();
    for (int i = tid; i < n; i += 256) {
        const int2 e = (i < BCAP) ? buf[i] : tmp[beg + i];
        const int r = e.x >> 16;
        const int pos = atomicAdd(&h[r], 1);
        tmp[beg + pos] = make_int2(e.x & 0xFFFF, e.y);
    }
}

// ---------- FUSED gather + GEMM: out[n,o] = sum_e z[n,e]*(hi[n,:]@W[e]) + x[n,o]
// Phase 1 (per block): gather this block's 128 hi-rows straight into A_lds
// as bf16 (each of 16 waves gathers 8 rows; per-lane 8B swizzled ds_write).
// Kills the 128 MB hi round-trip and overlaps gather (random-L2-bound) of one
// block with GEMM (L1/LDS/matrix-bound) of the co-resident block.
// Phase 2: barrier-free main loop, B fragments direct from fragment-major
// WbT (L2/L1), per-step-per-mi z-fold (register-solvent: ~55 VGPR measured).
#define BM 128
__global__ __launch_bounds__(1024, 4)
void moe_gemm(const u32* __restrict__ xq, const int2* __restrict__ scv,
              const int* __restrict__ offsets, const int* __restrict__ rend,
              const float* __restrict__ z, const short* __restrict__ WbT,
              const float* __restrict__ x, float* __restrict__ out) {
    __shared__ short A_lds[4][BM * 64];      // 4 x 16 KB: slice i0b, rows of 128B
    __shared__ float z_t[KE][BM];            // 4 KB, transposed
    const int tid  = threadIdx.x;
    const int lane = tid & 63;
    const int w    = tid >> 6;      // 0..15
    const int wr   = w >> 2;        // 0..3 : 32-row band
    const int wc   = w & 3;         // 0..3 : 64-col band
    const int row0 = blockIdx.x * BM;

    z_t[tid & 7][tid >> 3] = z[(size_t)row0 * KE + tid];   // BM*KE == 1024

    // ---- Phase 1: fused gather. Wave w produces rows m = w*8 .. w*8+7.
    // Lane holds k = 4*lane .. 4*lane+3  ->  slice = lane>>4; within-row byte
    // (pre-swizzle) = (lane&15)*8; swizzle acts on the 16B slot bits.
    {
        const int sl    = lane >> 4;
        const int base8 = (lane & 15) * 8;
        const int slotx = ((base8 >> 4) * 16);
        const int sub8  = base8 & 8;
        for (int ri = 0; ri < 8; ++ri) {
            const int m   = w * 8 + ri;
            const int row = row0 + m;
            const int beg = offsets[row];
            const int end = rend[row];
            float4 acc = {0.f, 0.f, 0.f, 0.f};
            int j = beg;
            for (; j + 8 <= end; j += 8) {
                int2 cc[8];
                u32  rr[8];
                #pragma unroll
                for (int q = 0; q < 8; ++q) cc[q] = scv[j + q];
                #pragma unroll
                for (int q = 0; q < 8; ++q)
                    rr[q] = (xq + (size_t)cc[q].x * (F / 4))[lane];
                #pragma unroll
                for (int q = 0; q < 8; ++q) {
                    const float v = __int_as_float(cc[q].y);
                    const f32x2 lo = __builtin_amdgcn_cvt_pk_f32_fp8(rr[q], false);
                    const f32x2 hi2 = __builtin_amdgcn_cvt_pk_f32_fp8(rr[q], true);
                    acc.x += v * lo[0];  acc.y += v * lo[1];
                    acc.z += v * hi2[0]; acc.w += v * hi2[1];
                }
            }
            for (; j < end; ++j) {
                const int2 c0 = scv[j];
                const u32 r0 = (xq + (size_t)c0.x * (F / 4))[lane];
                const float v0 = __int_as_float(c0.y);
                const f32x2 lo = __builtin_amdgcn_cvt_pk_f32_fp8(r0, false);
                const f32x2 hi2 = __builtin_amdgcn_cvt_pk_f32_fp8(r0, true);
                acc.x += v0 * lo[0];  acc.y += v0 * lo[1];
                acc.z += v0 * hi2[0]; acc.w += v0 * hi2[1];
            }
            union { short s[4]; int2 i2; } o;
            o.s[0] = f2bf(acc.x); o.s[1] = f2bf(acc.y);
            o.s[2] = f2bf(acc.z); o.s[3] = f2bf(acc.w);
            const int byte = m * 128 + (slotx ^ ((m & 7) << 4)) + sub8;
            *(int2*)((char*)&A_lds[sl][0] + byte) = o.i2;
        }
    }
    __syncthreads();   // the ONLY barrier: A/z ready for all waves

    // ---- Phase 2: barrier-free GEMM main loop (round-17, proven)
    f32x4 acc_t[2][4];
    #pragma unroll
    for (int mi = 0; mi < 2; ++mi)
        #pragma unroll
        for (int ni = 0; ni < 4; ++ni)
            acc_t[mi][ni] = (f32x4){0.f, 0.f, 0.f, 0.f};

    const int lr    = lane & 15;
    const int kq16  = (lane >> 4) * 16;    // 16B k-offset within 64B half
    const int rbase = (lane >> 4) * 4;

    // per-wave B base: chunk (wc*32 + s)*8 + nk, each chunk 64 lanes x 16B
    const short* Bw = WbT + ((size_t)wc * 256 << 9) + lane * 8;

    #pragma unroll 1
    for (int s = 0; s < 32; ++s) {
        const int e = s >> 2;

        short8 bf[8];                        // transient: 32 VGPR
        const short* ps = Bw + ((size_t)s * 8 << 9);
        #pragma unroll
        for (int nk = 0; nk < 8; ++nk)
            bf[nk] = *(const short8*)(ps + ((size_t)nk << 9));

        #pragma unroll
        for (int mi = 0; mi < 2; ++mi) {
            const int m = wr * 32 + mi * 16 + lr;
            short8 af[2];
            #pragma unroll
            for (int ks = 0; ks < 2; ++ks) {
                const int slot = ks * 64 + kq16;
                af[ks] = *(const short8*)((const char*)&A_lds[s & 3][0]
                            + m * 128 + (slot ^ ((m & 7) << 4)));
            }
            f32x4 pe[4];
            #pragma unroll
            for (int ni = 0; ni < 4; ++ni) pe[ni] = (f32x4){0.f, 0.f, 0.f, 0.f};
            #pragma unroll
            for (int ks = 0; ks < 2; ++ks)
                #pragma unroll
                for (int ni = 0; ni < 4; ++ni)
                    pe[ni] = __builtin_amdgcn_mfma_f32_16x16x32_bf16(
                        af[ks], bf[ni * 2 + ks], pe[ni], 0, 0, 0);
            const f32x4 zv = *(const f32x4*)&z_t[e][wr * 32 + mi * 16 + rbase];
            #pragma unroll
            for (int ni = 0; ni < 4; ++ni)
                #pragma unroll
                for (int r = 0; r < 4; ++r)
                    acc_t[mi][ni][r] += zv[r] * pe[ni][r];
        }
    }

    #pragma unroll
    for (int mi = 0; mi < 2; ++mi) {
        #pragma unroll
        for (int r = 0; r < 4; ++r) {
            const int m = wr * 32 + mi * 16 + rbase + r;
            const size_t rowoff = (size_t)(row0 + m) * F;
            #pragma unroll
            for (int ni = 0; ni < 4; ++ni) {
                const int o = wc * 64 + ni * 16 + lr;
                out[rowoff + o] = acc_t[mi][ni][r] + x[rowoff + o];
            }
        }
    }
}

extern "C" void kernel_launch(void* const* d_in, const int* in_sizes, int n_in,
                              void* d_out, int out_size, void* d_ws, size_t ws_size,
                              hipStream_t stream) {
    const float* x    = (const float*)d_in[0];
    // d_in[1] = h0 : unused by the reference (variant=False path)
    const float* z    = (const float*)d_in[2];
    const float* vals = (const float*)d_in[3];
    const float* W    = (const float*)d_in[4];
    const int* rows   = (const int*)d_in[5];
    const int* cols   = (const int*)d_in[6];
    float* out        = (float*)d_out;
    const int E = in_sizes[3];

    // workspace layout (~42 MB total)
    char* ws = (char*)d_ws;
    u32*   xq      = (u32*)  (ws);                               // 16 MB fp8 [NN][F]
    short* WbT     = (short*)(ws + ((size_t)16 << 20));          // 1 MB fragment-major
    int*   offsets = (int*)  (ws + ((size_t)17 << 20));          // 256 KB
    int*   rend    = (int*)  (ws + ((size_t)17 << 20) + 256*1024);   // 256 KB
    int*   bcursor = (int*)  (ws + ((size_t)17 << 20) + 512*1024);   // 1 KB
    int2*  tmp     = (int2*) (ws + ((size_t)18 << 20));          // 24 MB (256*BCAP*8B)

    const int nblk = (E + EPB - 1) / EPB;
    conv_x8<<<(NN * F) / (256 * 8), 256, 0, stream>>>(x, xq, bcursor);
    prep_w<<<dim3(4, 4, 8), 256, 0, stream>>>(W, WbT);
    bucket_scatter<<<nblk, 256, 0, stream>>>(rows, cols, vals, bcursor, tmp, E);
    bucket_to_csr<<<NB, 256, 0, stream>>>(bcursor, tmp, offsets, rend);
    moe_gemm<<<NN / BM, 1024, 0, stream>>>(xq, tmp, offsets, rend, z, WbT, x, out);
}

// Round 19
// 242.131 us; speedup vs baseline: 1.0705x; 1.0705x over previous
//
#include <hip/hip_runtime.h>
#include <hip/hip_bf16.h>

using short8 = __attribute__((ext_vector_type(8))) short;
using f32x4  = __attribute__((ext_vector_type(4))) float;
using f32x2  = __attribute__((ext_vector_type(2))) float;
typedef unsigned int u32;

static constexpr int NN = 65536;   // nodes
static constexpr int F  = 256;     // feat dim
static constexpr int KE = 8;       // experts
static constexpr int KD = KE * F;  // 2048 = GEMM inner dim
static constexpr int NB = 256;     // coarse buckets (row>>8)
static constexpr int EPB = 8192;   // edges per bucket_scatter block
static constexpr int BCAP = 12288; // fixed bucket capacity (mean 8192 + 45 sigma)

__device__ __forceinline__ short f2bf(float f) {
    union { __hip_bfloat16 h; short s; } u;
    u.h = __float2bfloat16(f);
    return u.s;
}

// ---------- x f32 -> xq fp8 e4m3; block 0 also initializes bucket cursors
__global__ __launch_bounds__(256)
void conv_x8(const float* __restrict__ x, u32* __restrict__ xq,
             int* __restrict__ bcursor) {
    if (blockIdx.x == 0 && threadIdx.x < NB)
        bcursor[threadIdx.x] = threadIdx.x * BCAP;
    const size_t i = ((size_t)blockIdx.x * 256 + threadIdx.x) * 8;
    const float4 a = *(const float4*)(x + i);
    const float4 b = *(const float4*)(x + i + 4);
    u32 w0 = __builtin_amdgcn_cvt_pk_fp8_f32(a.x, a.y, 0, false);
    w0     = __builtin_amdgcn_cvt_pk_fp8_f32(a.z, a.w, w0, true);
    u32 w1 = __builtin_amdgcn_cvt_pk_fp8_f32(b.x, b.y, 0, false);
    w1     = __builtin_amdgcn_cvt_pk_fp8_f32(b.z, b.w, w1, true);
    *(uint2*)(xq + i / 4) = make_uint2(w0, w1);
}

// ---------- W [8][256][256] f32 -> WbT fragment-major bf16 (round-12 layout,
// correctness-proven): chunk = ((wc*32 + s)*8 + nk) of 64 lanes x 16B, where
// s = e*4 + i0b, nk = ni*2+ks, lane = hi2*16+lr holds
// W[e][i0b*64 + ks*32 + hi2*8 + j][wc*64 + ni*16 + lr], j=0..7.
__global__ void prep_w(const float* __restrict__ W, short* __restrict__ WbT) {
    __shared__ float tile[64][65];
    const int e   = blockIdx.z;
    const int i0b = blockIdx.x;         // i-tile
    const int wc  = blockIdx.y;         // o-tile
    const int c  = threadIdx.x & 63;
    const int r4 = threadIdx.x >> 6;
    for (int rr = r4; rr < 64; rr += 4)
        tile[rr][c] = W[((size_t)e * F + i0b * 64 + rr) * F + wc * 64 + c];
    __syncthreads();
    const int s = e * 4 + i0b;
    #pragma unroll
    for (int q = 0; q < 2; ++q) {
        const int ci   = threadIdx.x + q * 256;   // 0..511
        const int nk   = ci >> 6;
        const int lane = ci & 63;
        const int ni = nk >> 1, ks = nk & 1;
        const int hi2 = lane >> 4, lr = lane & 15;
        const int o_l = ni * 16 + lr;
        const int i_l = ks * 32 + hi2 * 8;
        short8 pk;
        #pragma unroll
        for (int j = 0; j < 8; ++j) pk[j] = f2bf(tile[i_l + j][o_l]);
        *(short8*)(WbT + ((((size_t)(wc * 32 + s) * 8 + nk) << 6) + lane) * 8) = pk;
    }
}

// ---------- scatter edges into FIXED-CAPACITY coarse buckets
__global__ __launch_bounds__(256)
void bucket_scatter(const int* __restrict__ rows, const int* __restrict__ cols,
                    const float* __restrict__ vals, int* __restrict__ bcursor,
                    int2* __restrict__ tmp, int E) {
    __shared__ int h[NB], wb[NB];
    const int tid = threadIdx.x;
    h[tid] = 0;
    __syncthreads();
    const int base = blockIdx.x * EPB;
    const int lim  = min(EPB, E - base);
    for (int i = tid; i < lim; i += 256)
        atomicAdd(&h[rows[base + i] >> 8], 1);
    __syncthreads();
    const int c = h[tid];
    wb[tid] = c ? atomicAdd(&bcursor[tid], c) : 0;
    h[tid] = 0;
    __syncthreads();
    for (int i = tid; i < lim; i += 256) {
        const int r  = rows[base + i];
        const int bk = r >> 8;
        const int rank = atomicAdd(&h[bk], 1);
        tmp[wb[bk] + rank] = make_int2(((r & 255) << 16) | cols[base + i],
                                       __float_as_int(vals[base + i]));
    }
}

// ---------- one block per bucket: exact-row sort (in place) + row starts/ends
__global__ __launch_bounds__(256)
void bucket_to_csr(const int* __restrict__ bcursor, int2* __restrict__ tmp,
                   int* __restrict__ offsets, int* __restrict__ rend) {
    __shared__ int2 buf[BCAP];          // 96 KB
    __shared__ int h[NB], off[NB];
    const int tid = threadIdx.x;
    const int k   = blockIdx.x;
    const int beg = k * BCAP;
    const int n   = bcursor[k] - beg;
    h[tid] = 0;
    __syncthreads();
    for (int i = tid; i < n; i += 256) {
        const int2 e = tmp[beg + i];
        if (i < BCAP) buf[i] = e;
        atomicAdd(&h[e.x >> 16], 1);
    }
    __syncthreads();
    const int c = h[tid];
    off[tid] = c;
    __syncthreads();
    for (int o = 1; o < NB; o <<= 1) {
        int v = (tid >= o) ? off[tid - o] : 0;
        __syncthreads();
        off[tid] += v;
        __syncthreads();
    }
    const int excl = off[tid] - c;
    offsets[k * NB + tid] = beg + excl;
    rend[k * NB + tid]    = beg + excl + c;
    h[tid] = excl;                      // reuse as within-bucket cursor
    __syncthreads();
    for (int i = tid; i < n; i += 256) {
        const int2 e = (i < BCAP) ? buf[i] : tmp[beg + i];
        const int r = e.x >> 16;
        const int pos = atomicAdd(&h[r], 1);
        tmp[beg + pos] = make_int2(e.x & 0xFFFF, e.y);
    }
}

// ---------- gather: per-row segmented accumulate (fp8 x), hi written f32 into d_out
__global__ __launch_bounds__(256)
void gather_rows(const u32* __restrict__ xq, const int2* __restrict__ scv,
                 const int* __restrict__ offsets, const int* __restrict__ rend,
                 float* __restrict__ hi) {
    const int lane = threadIdx.x & 63;
    int row = (blockIdx.x << 2) + (threadIdx.x >> 6);
    row = __builtin_amdgcn_readfirstlane(row);
    const int beg = offsets[row];
    const int end = rend[row];
    float4 acc = {0.f, 0.f, 0.f, 0.f};
    int j = beg;
    for (; j + 8 <= end; j += 8) {
        int2 cc[8];
        u32  rr[8];
        #pragma unroll
        for (int q = 0; q < 8; ++q) cc[q] = scv[j + q];
        #pragma unroll
        for (int q = 0; q < 8; ++q)
            rr[q] = (xq + (size_t)cc[q].x * (F / 4))[lane];
        #pragma unroll
        for (int q = 0; q < 8; ++q) {
            const float v = __int_as_float(cc[q].y);
            const f32x2 lo = __builtin_amdgcn_cvt_pk_f32_fp8(rr[q], false);
            const f32x2 hi2 = __builtin_amdgcn_cvt_pk_f32_fp8(rr[q], true);
            acc.x += v * lo[0];  acc.y += v * lo[1];
            acc.z += v * hi2[0]; acc.w += v * hi2[1];
        }
    }
    for (; j < end; ++j) {
        const int2 c0 = scv[j];
        const u32 r0 = (xq + (size_t)c0.x * (F / 4))[lane];
        const float v0 = __int_as_float(c0.y);
        const f32x2 lo = __builtin_amdgcn_cvt_pk_f32_fp8(r0, false);
        const f32x2 hi2 = __builtin_amdgcn_cvt_pk_f32_fp8(r0, true);
        acc.x += v0 * lo[0];  acc.y += v0 * lo[1];
        acc.z += v0 * hi2[0]; acc.w += v0 * hi2[1];
    }
    ((float4*)(hi + (size_t)row * F))[lane] = acc;
}

// ---------- GEMM: out[n,o] = sum_e z[n,e] * (hi[n,:] @ W[e]) + x[n,o]
// Round-17 proven structure: barrier-free main loop at the 32x64 wave tile.
// A (64 KB) + z_t in LDS, written once, read-only after one prologue sync.
// B fragments loaded per step DIRECTLY from fragment-major WbT (L2/L1).
// Unified-file ledger: acc 32 + pe 16 + bf 32 + af 16 + misc ~15 <= 128
// (measured VGPR_Count 52, no scratch).
#define BM 128
__global__ __launch_bounds__(1024, 4)
void moe_gemm(const float* __restrict__ hi, const float* __restrict__ z,
              const short* __restrict__ WbT, const float* __restrict__ x,
              float* __restrict__ out) {
    __shared__ short A_lds[4][BM * 64];      // 4 x 16 KB: slice i0b, rows of 128B
    __shared__ float z_t[KE][BM];            // 4 KB, transposed
    const int tid  = threadIdx.x;
    const int lane = tid & 63;
    const int w    = tid >> 6;      // 0..15
    const int wr   = w >> 2;        // 0..3 : 32-row band
    const int wc   = w & 3;         // 0..3 : 64-col band
    const int row0 = blockIdx.x * BM;

    z_t[tid & 7][tid >> 3] = z[(size_t)row0 * KE + tid];   // BM*KE == 1024
    {   // stage A: hi f32 -> bf16, slice layout + (m&7) swizzle
        const int m0 = tid >> 5;       // 32 rows per pass
        const int c8 = tid & 31;       // 8-float chunk: slice c8>>3, 16B slot c8&7
        for (int p = 0; p < BM / 32; ++p) {
            const int m = p * 32 + m0;
            const float4* src = (const float4*)(hi + (size_t)(row0 + m) * F + c8 * 8);
            const float4 a = src[0], b = src[1];
            short8 pk;
            pk[0]=f2bf(a.x); pk[1]=f2bf(a.y); pk[2]=f2bf(a.z); pk[3]=f2bf(a.w);
            pk[4]=f2bf(b.x); pk[5]=f2bf(b.y); pk[6]=f2bf(b.z); pk[7]=f2bf(b.w);
            const int byte = m * 128 + (((c8 & 7) * 16) ^ ((m & 7) << 4));
            *(short8*)((char*)&A_lds[c8 >> 3][0] + byte) = pk;
        }
    }
    __syncthreads();   // the ONLY barrier: A/z ready for all waves

    f32x4 acc_t[2][4];
    #pragma unroll
    for (int mi = 0; mi < 2; ++mi)
        #pragma unroll
        for (int ni = 0; ni < 4; ++ni)
            acc_t[mi][ni] = (f32x4){0.f, 0.f, 0.f, 0.f};

    const int lr    = lane & 15;
    const int kq16  = (lane >> 4) * 16;    // 16B k-offset within 64B half
    const int rbase = (lane >> 4) * 4;

    // per-wave B base: chunk (wc*32 + s)*8 + nk, each chunk 64 lanes x 16B
    const short* Bw = WbT + ((size_t)wc * 256 << 9) + lane * 8;

    #pragma unroll 1
    for (int s = 0; s < 32; ++s) {
        const int e = s >> 2;

        short8 bf[8];                        // transient: 32 VGPR
        const short* ps = Bw + ((size_t)s * 8 << 9);
        #pragma unroll
        for (int nk = 0; nk < 8; ++nk)
            bf[nk] = *(const short8*)(ps + ((size_t)nk << 9));

        #pragma unroll
        for (int mi = 0; mi < 2; ++mi) {
            const int m = wr * 32 + mi * 16 + lr;
            short8 af[2];
            #pragma unroll
            for (int ks = 0; ks < 2; ++ks) {
                const int slot = ks * 64 + kq16;
                af[ks] = *(const short8*)((const char*)&A_lds[s & 3][0]
                            + m * 128 + (slot ^ ((m & 7) << 4)));
            }
            f32x4 pe[4];
            #pragma unroll
            for (int ni = 0; ni < 4; ++ni) pe[ni] = (f32x4){0.f, 0.f, 0.f, 0.f};
            #pragma unroll
            for (int ks = 0; ks < 2; ++ks)
                #pragma unroll
                for (int ni = 0; ni < 4; ++ni)
                    pe[ni] = __builtin_amdgcn_mfma_f32_16x16x32_bf16(
                        af[ks], bf[ni * 2 + ks], pe[ni], 0, 0, 0);
            const f32x4 zv = *(const f32x4*)&z_t[e][wr * 32 + mi * 16 + rbase];
            #pragma unroll
            for (int ni = 0; ni < 4; ++ni)
                #pragma unroll
                for (int r = 0; r < 4; ++r)
                    acc_t[mi][ni][r] += zv[r] * pe[ni][r];
        }
    }

    #pragma unroll
    for (int mi = 0; mi < 2; ++mi) {
        #pragma unroll
        for (int r = 0; r < 4; ++r) {
            const int m = wr * 32 + mi * 16 + rbase + r;
            const size_t rowoff = (size_t)(row0 + m) * F;
            #pragma unroll
            for (int ni = 0; ni < 4; ++ni) {
                const int o = wc * 64 + ni * 16 + lr;
                out[rowoff + o] = acc_t[mi][ni][r] + x[rowoff + o];
            }
        }
    }
}

extern "C" void kernel_launch(void* const* d_in, const int* in_sizes, int n_in,
                              void* d_out, int out_size, void* d_ws, size_t ws_size,
                              hipStream_t stream) {
    const float* x    = (const float*)d_in[0];
    // d_in[1] = h0 : unused by the reference (variant=False path)
    const float* z    = (const float*)d_in[2];
    const float* vals = (const float*)d_in[3];
    const float* W    = (const float*)d_in[4];
    const int* rows   = (const int*)d_in[5];
    const int* cols   = (const int*)d_in[6];
    float* out        = (float*)d_out;
    const int E = in_sizes[3];

    // workspace layout (~42 MB total)
    char* ws = (char*)d_ws;
    u32*   xq      = (u32*)  (ws);                               // 16 MB fp8 [NN][F]
    short* WbT     = (short*)(ws + ((size_t)16 << 20));          // 1 MB fragment-major
    int*   offsets = (int*)  (ws + ((size_t)17 << 20));          // 256 KB
    int*   rend    = (int*)  (ws + ((size_t)17 << 20) + 256*1024);   // 256 KB
    int*   bcursor = (int*)  (ws + ((size_t)17 << 20) + 512*1024);   // 1 KB
    int2*  tmp     = (int2*) (ws + ((size_t)18 << 20));          // 24 MB (256*BCAP*8B)
    float* hi      = out;    // gather output lives in d_out; moe_gemm is in-place

    const int nblk = (E + EPB - 1) / EPB;
    conv_x8<<<(NN * F) / (256 * 8), 256, 0, stream>>>(x, xq, bcursor);
    prep_w<<<dim3(4, 4, 8), 256, 0, stream>>>(W, WbT);
    bucket_scatter<<<nblk, 256, 0, stream>>>(rows, cols, vals, bcursor, tmp, E);
    bucket_to_csr<<<NB, 256, 0, stream>>>(bcursor, tmp, offsets, rend);
    gather_rows<<<NN / 4, 256, 0, stream>>>(xq, tmp, offsets, rend, hi);
    moe_gemm<<<NN / BM, 1024, 0, stream>>>(hi, z, WbT, x, out);
}

// Round 20
// 203.937 us; speedup vs baseline: 1.2709x; 1.1873x over previous
//
#include <hip/hip_runtime.h>
#include <hip/hip_bf16.h>

using short8 = __attribute__((ext_vector_type(8))) short;
using f32x4  = __attribute__((ext_vector_type(4))) float;
using f32x2  = __attribute__((ext_vector_type(2))) float;
using long2v = __attribute__((ext_vector_type(2))) long;
typedef unsigned int u32;

static constexpr int NN = 65536;   // nodes
static constexpr int F  = 256;     // feat dim
static constexpr int KE = 8;       // experts
static constexpr int NB = 256;     // coarse buckets (row>>8)
static constexpr int EPB = 8192;   // edges per bucket_scatter block
static constexpr int BCAP = 12288; // fixed bucket capacity (mean 8192 + 45 sigma)

__device__ __forceinline__ u32 pk4_fp8(float a, float b, float c, float d) {
    u32 p = __builtin_amdgcn_cvt_pk_fp8_f32(a, b, 0, false);
    return __builtin_amdgcn_cvt_pk_fp8_f32(c, d, p, true);
}

// ---------- x f32 -> xq fp8 e4m3; block 0 also initializes bucket cursors
__global__ __launch_bounds__(256)
void conv_x8(const float* __restrict__ x, u32* __restrict__ xq,
             int* __restrict__ bcursor) {
    if (blockIdx.x == 0 && threadIdx.x < NB)
        bcursor[threadIdx.x] = threadIdx.x * BCAP;
    const size_t i = ((size_t)blockIdx.x * 256 + threadIdx.x) * 8;
    const float4 a = *(const float4*)(x + i);
    const float4 b = *(const float4*)(x + i + 4);
    *(uint2*)(xq + i / 4) = make_uint2(pk4_fp8(a.x, a.y, a.z, a.w),
                                       pk4_fp8(b.x, b.y, b.z, b.w));
}

// ---------- W [8][256][256] f32 -> WbT8 fragment-major FP8 e4m3:
// chunk = ((wc*32 + s)*4 + ni), 64 lanes x 16B (1 KB); s = e*4 + i0b.
// lane = hi2*16+lr: bytes 0-7 = ks0 frag, 8-15 = ks1 frag, where frag(ks) =
// W[e][i0b*64 + ks*32 + hi2*8 + j][wc*64 + ni*16 + lr], j=0..7 (fp8 each).
__global__ void prep_w(const float* __restrict__ W, u32* __restrict__ WbT8) {
    __shared__ float tile[64][65];
    const int e   = blockIdx.z;
    const int i0b = blockIdx.x;         // i-tile
    const int wc  = blockIdx.y;         // o-tile
    const int c  = threadIdx.x & 63;
    const int r4 = threadIdx.x >> 6;
    for (int rr = r4; rr < 64; rr += 4)
        tile[rr][c] = W[((size_t)e * F + i0b * 64 + rr) * F + wc * 64 + c];
    __syncthreads();
    const int s    = e * 4 + i0b;
    const int ni   = threadIdx.x >> 6;  // chunk within step
    const int lane = threadIdx.x & 63;
    const int hi2 = lane >> 4, lr = lane & 15;
    const int o_l = ni * 16 + lr;
    uint4 outv;
    u32* ov = (u32*)&outv;
    #pragma unroll
    for (int ks = 0; ks < 2; ++ks) {
        const int i_l = ks * 32 + hi2 * 8;
        ov[ks * 2 + 0] = pk4_fp8(tile[i_l + 0][o_l], tile[i_l + 1][o_l],
                                 tile[i_l + 2][o_l], tile[i_l + 3][o_l]);
        ov[ks * 2 + 1] = pk4_fp8(tile[i_l + 4][o_l], tile[i_l + 5][o_l],
                                 tile[i_l + 6][o_l], tile[i_l + 7][o_l]);
    }
    *(uint4*)((char*)WbT8 + (((size_t)(wc * 32 + s) * 4 + ni) << 10) + lane * 16) = outv;
}

// ---------- scatter edges into FIXED-CAPACITY coarse buckets
__global__ __launch_bounds__(256)
void bucket_scatter(const int* __restrict__ rows, const int* __restrict__ cols,
                    const float* __restrict__ vals, int* __restrict__ bcursor,
                    int2* __restrict__ tmp, int E) {
    __shared__ int h[NB], wb[NB];
    const int tid = threadIdx.x;
    h[tid] = 0;
    __syncthreads();
    const int base = blockIdx.x * EPB;
    const int lim  = min(EPB, E - base);
    for (int i = tid; i < lim; i += 256)
        atomicAdd(&h[rows[base + i] >> 8], 1);
    __syncthreads();
    const int c = h[tid];
    wb[tid] = c ? atomicAdd(&bcursor[tid], c) : 0;
    h[tid] = 0;
    __syncthreads();
    for (int i = tid; i < lim; i += 256) {
        const int r  = rows[base + i];
        const int bk = r >> 8;
        const int rank = atomicAdd(&h[bk], 1);
        tmp[wb[bk] + rank] = make_int2(((r & 255) << 16) | cols[base + i],
                                       __float_as_int(vals[base + i]));
    }
}

// ---------- one block per bucket: exact-row sort (in place) + row starts/ends
__global__ __launch_bounds__(256)
void bucket_to_csr(const int* __restrict__ bcursor, int2* __restrict__ tmp,
                   int* __restrict__ offsets, int* __restrict__ rend) {
    __shared__ int2 buf[BCAP];          // 96 KB
    __shared__ int h[NB], off[NB];
    const int tid = threadIdx.x;
    const int k   = blockIdx.x;
    const int beg = k * BCAP;
    const int n   = bcursor[k] - beg;
    h[tid] = 0;
    __syncthreads();
    for (int i = tid; i < n; i += 256) {
        const int2 e = tmp[beg + i];
        if (i < BCAP) buf[i] = e;
        atomicAdd(&h[e.x >> 16], 1);
    }
    __syncthreads();
    const int c = h[tid];
    off[tid] = c;
    __syncthreads();
    for (int o = 1; o < NB; o <<= 1) {
        int v = (tid >= o) ? off[tid - o] : 0;
        __syncthreads();
        off[tid] += v;
        __syncthreads();
    }
    const int excl = off[tid] - c;
    offsets[k * NB + tid] = beg + excl;
    rend[k * NB + tid]    = beg + excl + c;
    h[tid] = excl;                      // reuse as within-bucket cursor
    __syncthreads();
    for (int i = tid; i < n; i += 256) {
        const int2 e = (i < BCAP) ? buf[i] : tmp[beg + i];
        const int r = e.x >> 16;
        const int pos = atomicAdd(&h[r], 1);
        tmp[beg + pos] = make_int2(e.x & 0xFFFF, e.y);
    }
}

// ---------- gather: per-row segmented accumulate (fp8 x), hi written FP8
__global__ __launch_bounds__(256)
void gather_rows(const u32* __restrict__ xq, const int2* __restrict__ scv,
                 const int* __restrict__ offsets, const int* __restrict__ rend,
                 u32* __restrict__ hiq) {
    const int lane = threadIdx.x & 63;
    int row = (blockIdx.x << 2) + (threadIdx.x >> 6);
    row = __builtin_amdgcn_readfirstlane(row);
    const int beg = offsets[row];
    const int end = rend[row];
    float4 acc = {0.f, 0.f, 0.f, 0.f};
    int j = beg;
    for (; j + 8 <= end; j += 8) {
        int2 cc[8];
        u32  rr[8];
        #pragma unroll
        for (int q = 0; q < 8; ++q) cc[q] = scv[j + q];
        #pragma unroll
        for (int q = 0; q < 8; ++q)
            rr[q] = (xq + (size_t)cc[q].x * (F / 4))[lane];
        #pragma unroll
        for (int q = 0; q < 8; ++q) {
            const float v = __int_as_float(cc[q].y);
            const f32x2 lo = __builtin_amdgcn_cvt_pk_f32_fp8(rr[q], false);
            const f32x2 hi2 = __builtin_amdgcn_cvt_pk_f32_fp8(rr[q], true);
            acc.x += v * lo[0];  acc.y += v * lo[1];
            acc.z += v * hi2[0]; acc.w += v * hi2[1];
        }
    }
    for (; j < end; ++j) {
        const int2 c0 = scv[j];
        const u32 r0 = (xq + (size_t)c0.x * (F / 4))[lane];
        const float v0 = __int_as_float(c0.y);
        const f32x2 lo = __builtin_amdgcn_cvt_pk_f32_fp8(r0, false);
        const f32x2 hi2 = __builtin_amdgcn_cvt_pk_f32_fp8(r0, true);
        acc.x += v0 * lo[0];  acc.y += v0 * lo[1];
        acc.z += v0 * hi2[0]; acc.w += v0 * hi2[1];
    }
    // lane holds k = 4*lane .. 4*lane+3 -> one u32 of 4 fp8, row = 256 B
    hiq[(size_t)row * 64 + lane] = pk4_fp8(acc.x, acc.y, acc.z, acc.w);
}

// ---------- GEMM (FP8 MFMA): out[n,o] = sum_e z[n,e]*(hi[n,:]@W[e]) + x[n,o]
// Round-17 barrier-free structure with fp8 operands: halves B L1 traffic
// (4 KB/wave/step) and A LDS traffic (b64 reads, 32 KB tile). Non-scaled
// fp8 MFMA = bf16 rate, so operand bandwidth is the only term that moves.
// A_lds rows 64 B, swizzle on 8B units: byte = m*64 + ((slot ^ (m&7))<<3)
// -> 2-way max (free). Ledger: acc 32 + pe 16 + bf 16 + af 4 + misc ~15 << 128.
#define BM 128
__global__ __launch_bounds__(1024, 4)
void moe_gemm(const u32* __restrict__ hiq, const float* __restrict__ z,
              const u32* __restrict__ WbT8, const float* __restrict__ x,
              float* __restrict__ out) {
    __shared__ char A_lds[4][BM * 64];       // 4 x 8 KB: slice i0b, rows of 64B fp8
    __shared__ float z_t[KE][BM];            // 4 KB, transposed
    const int tid  = threadIdx.x;
    const int lane = tid & 63;
    const int w    = tid >> 6;      // 0..15
    const int wr   = w >> 2;        // 0..3 : 32-row band
    const int wc   = w & 3;         // 0..3 : 64-col band
    const int row0 = blockIdx.x * BM;

    z_t[tid & 7][tid >> 3] = z[(size_t)row0 * KE + tid];   // BM*KE == 1024
    {   // stage A: copy fp8 hi rows into sliced+swizzled LDS (8B units, 4 passes)
        for (int p = 0; p < 4; ++p) {
            const int u    = p * 1024 + tid;
            const int m    = u >> 5;           // row 0..127
            const int ku8  = u & 31;           // 8B unit within 256B row
            const int sl   = ku8 >> 3;         // k-slice 0..3
            const int slot = ku8 & 7;          // 8B slot within 64B slice-row
            const uint2 v = *(const uint2*)(hiq + (size_t)(row0 + m) * 64 + ku8 * 2);
            *(uint2*)(&A_lds[sl][0] + m * 64 + ((slot ^ (m & 7)) << 3)) = v;
        }
    }
    __syncthreads();   // the ONLY barrier: A/z ready for all waves

    f32x4 acc_t[2][4];
    #pragma unroll
    for (int mi = 0; mi < 2; ++mi)
        #pragma unroll
        for (int ni = 0; ni < 4; ++ni)
            acc_t[mi][ni] = (f32x4){0.f, 0.f, 0.f, 0.f};

    const int lr    = lane & 15;
    const int hi2   = lane >> 4;
    const int rbase = hi2 * 4;

    // per-wave B base: chunk (wc*32 + s)*4 + ni, each chunk 64 lanes x 16B
    const char* Bw = (const char*)WbT8 + (((size_t)wc * 32 * 4) << 10) + lane * 16;

    #pragma unroll 1
    for (int s = 0; s < 32; ++s) {
        const int e = s >> 2;

        long2v bf[4];                        // transient: 16 VGPR (x = ks0, y = ks1)
        const char* ps = Bw + ((size_t)s * 4 << 10);
        #pragma unroll
        for (int ni = 0; ni < 4; ++ni)
            bf[ni] = *(const long2v*)(ps + ((size_t)ni << 10));

        #pragma unroll
        for (int mi = 0; mi < 2; ++mi) {
            const int m = wr * 32 + mi * 16 + lr;
            long af[2];
            #pragma unroll
            for (int ks = 0; ks < 2; ++ks) {
                const int slot = ks * 4 + hi2;
                af[ks] = *(const long*)(&A_lds[s & 3][0]
                            + m * 64 + ((slot ^ (m & 7)) << 3));
            }
            f32x4 pe[4];
            #pragma unroll
            for (int ni = 0; ni < 4; ++ni) pe[ni] = (f32x4){0.f, 0.f, 0.f, 0.f};
            #pragma unroll
            for (int ks = 0; ks < 2; ++ks)
                #pragma unroll
                for (int ni = 0; ni < 4; ++ni)
                    pe[ni] = __builtin_amdgcn_mfma_f32_16x16x32_fp8_fp8(
                        af[ks], ks ? bf[ni].y : bf[ni].x, pe[ni], 0, 0, 0);
            const f32x4 zv = *(const f32x4*)&z_t[e][wr * 32 + mi * 16 + rbase];
            #pragma unroll
            for (int ni = 0; ni < 4; ++ni)
                #pragma unroll
                for (int r = 0; r < 4; ++r)
                    acc_t[mi][ni][r] += zv[r] * pe[ni][r];
        }
    }

    #pragma unroll
    for (int mi = 0; mi < 2; ++mi) {
        #pragma unroll
        for (int r = 0; r < 4; ++r) {
            const int m = wr * 32 + mi * 16 + rbase + r;
            const size_t rowoff = (size_t)(row0 + m) * F;
            #pragma unroll
            for (int ni = 0; ni < 4; ++ni) {
                const int o = wc * 64 + ni * 16 + lr;
                out[rowoff + o] = acc_t[mi][ni][r] + x[rowoff + o];
            }
        }
    }
}

extern "C" void kernel_launch(void* const* d_in, const int* in_sizes, int n_in,
                              void* d_out, int out_size, void* d_ws, size_t ws_size,
                              hipStream_t stream) {
    const float* x    = (const float*)d_in[0];
    // d_in[1] = h0 : unused by the reference (variant=False path)
    const float* z    = (const float*)d_in[2];
    const float* vals = (const float*)d_in[3];
    const float* W    = (const float*)d_in[4];
    const int* rows   = (const int*)d_in[5];
    const int* cols   = (const int*)d_in[6];
    float* out        = (float*)d_out;
    const int E = in_sizes[3];

    // workspace layout (~58 MB; >=82 MB proven available in round 1)
    char* ws = (char*)d_ws;
    u32*   xq      = (u32*)  (ws);                               // 16 MB fp8 [NN][F]
    u32*   WbT8    = (u32*)  (ws + ((size_t)16 << 20));          // 512 KB fragment-major fp8
    int*   offsets = (int*)  (ws + ((size_t)17 << 20));          // 256 KB
    int*   rend    = (int*)  (ws + ((size_t)17 << 20) + 256*1024);   // 256 KB
    int*   bcursor = (int*)  (ws + ((size_t)17 << 20) + 512*1024);   // 1 KB
    int2*  tmp     = (int2*) (ws + ((size_t)18 << 20));          // 24 MB (256*BCAP*8B)
    u32*   hiq     = (u32*)  (ws + ((size_t)42 << 20));          // 16 MB fp8 [NN][F]

    const int nblk = (E + EPB - 1) / EPB;
    conv_x8<<<(NN * F) / (256 * 8), 256, 0, stream>>>(x, xq, bcursor);
    prep_w<<<dim3(4, 4, 8), 256, 0, stream>>>(W, WbT8);
    bucket_scatter<<<nblk, 256, 0, stream>>>(rows, cols, vals, bcursor, tmp, E);
    bucket_to_csr<<<NB, 256, 0, stream>>>(bcursor, tmp, offsets, rend);
    gather_rows<<<NN / 4, 256, 0, stream>>>(xq, tmp, offsets, rend, hiq);
    moe_gemm<<<NN / BM, 1024, 0, stream>>>(hiq, z, WbT8, x, out);
}